// Round 8
// baseline (128.292 us; speedup 1.0000x reference)
//
#include <hip/hip_runtime.h>

#define D    160
#define D2   (D * D)
#define D3   (D * D * D)
#define NB   4
#define TILE 4
#define HXL  3                           // x halo low
#define WINX 11                          // x slots [xt-3 .. xt+7]
#define HYL  3                           // y halo low
#define WINY 10                          // y slots [yt-3 .. yt+6]
#define ZSL  40                          // z-slab depth
#define HZL  4                           // z halo low (4 keeps 16B alignment)
#define ZWIN 48                          // z slots [zl-4 .. zl+43]
#define NROW (WINX * WINY)               // 110 staged (x,y) rows
#define LDSF (NROW * ZWIN)               // 5280 floats used
#define NSTAGE ((LDSF + 255) / 256)      // 21 global_load_lds per slab
#define LDSPAD (NSTAGE * 256)            // 5376 floats per buffer (21 KB)
#define TPB  640                         // 10 waves; 16 rows x 40 z -> 1 voxel/thread
#define NWAVE (TPB / 64)
#define KMAX ((NSTAGE + NWAVE - 1) / NWAVE)   // 3
#define TPD  (D / TILE)                  // 40
#define NZS  (D / ZSL)                   // 4 slabs
#define NTILE (NB * TPD * NZS * TPD)     // 25600 slab-tiles
#define NBLK 1280                        // 5 blocks/CU, 3 resident (42KB dbuf)
#define CNT  (NTILE / NBLK)              // 20 contiguous tiles per block

typedef float f32x2 __attribute__((ext_vector_type(2)));

// sid -> (b, xt, slab, yt): yt fastest so consecutive sids share x/z halo rows
__device__ __forceinline__ void sid_decode(int sid, int& b, int& xt, int& zl, int& yt) {
    yt = (sid % TPD) * TILE;
    int t = sid / TPD;
    zl = (t & (NZS - 1)) * ZSL;
    t >>= 2;
    xt = (t % TPD) * TILE;
    b  = t / TPD;
}

__device__ __forceinline__ void issue_ddf(const float* __restrict__ ddf, int sid,
                                          int rx, int ry, int zloc,
                                          float& dx, float& dy, float& dz, int& vb) {
    int b, xt, zl, yt;
    sid_decode(sid, b, xt, zl, yt);
    vb = b * D3 + (xt + rx) * D2 + (yt + ry) * D + (zl + zloc);
    const float* p = ddf + (size_t)vb * 3;
    dx = __builtin_nontemporal_load(p);
    dy = __builtin_nontemporal_load(p + 1);
    dz = __builtin_nontemporal_load(p + 2);
}

__device__ __forceinline__ void issue_stage(const float* __restrict__ image, int sid,
                                            int w, const int* sxp, const int* syp,
                                            const int* zop, float* buf) {
    int b, xt, zl, yt;
    sid_decode(sid, b, xt, zl, yt);
    const float* vol = image + (size_t)b * D3;
#pragma unroll
    for (int i = 0; i < KMAX; ++i) {
        int k = w + i * NWAVE;
        if (k < NSTAGE) {                 // wave-uniform
            int srcx = min(max(xt - HXL + sxp[i], 0), D - 1);
            int srcy = min(max(yt - HYL + syp[i], 0), D - 1);
            int srcz = min(max(zl - HZL + zop[i], 0), D - 4);   // 16B-aligned clamp
            const float* g = vol + srcx * D2 + srcy * D + srcz;
            __builtin_amdgcn_global_load_lds(
                (const __attribute__((address_space(1))) void*)g,
                (__attribute__((address_space(3))) void*)(buf + k * 256),
                16, 0, 0);
        }
    }
}

__device__ __forceinline__ void do_iter(
    const float* __restrict__ ddf, const float* __restrict__ image,
    float* __restrict__ out, int& sid, int& it,
    float& dxc, float& dyc, float& dzc,
    float& dxn, float& dyn, float& dzn,
    int& vbc, int& vbn,
    float* bufc, float* bufn,
    int rx, int ry, int zloc, int w,
    const int* sxp, const int* syp, const int* zop)
{
    const float maxf = (float)(D - 1);
    int bC, xtC, zlC, ytC;
    sid_decode(sid, bC, xtC, zlC, ytC);
    const float* volC = image + (size_t)bC * D3;

    // ---- phase A: coords, weights, masked fallback loads (issued EARLY) ----
    float fx = (float)(xtC + rx) + dxc;
    float fy = (float)(ytC + ry) + dyc;
    float fz = (float)(zlC + zloc) + dzc;
    fx = fminf(fmaxf(fx, 0.0f), maxf);
    fy = fminf(fmaxf(fy, 0.0f), maxf);
    fz = fminf(fmaxf(fz, 0.0f), maxf);
    int x0 = (int)fx, y0 = (int)fy, z0 = (int)fz;
    float wx = fx - (float)x0;
    float wy = fy - (float)y0;
    float wz = fz - (float)z0;

    int sx0 = x0 - xtC + HXL;
    int sy0 = y0 - ytC + HYL;
    int sz0 = z0 - zlC + HZL;
    bool inWin = ((unsigned)sx0 <= (unsigned)(WINX - 2)) &
                 ((unsigned)sy0 <= (unsigned)(WINY - 2)) &
                 ((unsigned)sz0 <= (unsigned)(ZWIN - 2));
    int cx = min(max(sx0, 0), WINX - 2);
    int cy = min(max(sy0, 0), WINY - 2);
    int cz = min(max(sz0, 0), ZWIN - 2);
    int base00 = (cx * WINY + cy) * ZWIN + cz;

    f32x2 fb00 = {}, fb01 = {}, fb10 = {}, fb11 = {};
    bool sh = false;
    if (!inWin) {                      // rare: |disp| beyond halo
        int x1 = min(x0 + 1, D - 1);
        int y1 = min(y0 + 1, D - 1);
        int zc = min(z0, D - 2);
        sh = z0 > zc;                  // z0 == 159 -> wz == 0
        fb00 = *(const f32x2*)(volC + x0 * D2 + y0 * D + zc);
        fb01 = *(const f32x2*)(volC + x0 * D2 + y1 * D + zc);
        fb10 = *(const f32x2*)(volC + x1 * D2 + y0 * D + zc);
        fb11 = *(const f32x2*)(volC + x1 * D2 + y1 * D + zc);
    }

    // keep fb loads OLDER than the stage loads (in-order vmcnt retirement)
    __builtin_amdgcn_sched_barrier(0);

    // ---- issue next tile's ddf + stage into the other buffer ----
    if (it + 1 < CNT) {
        issue_ddf(ddf, sid + 1, rx, ry, zloc, dxn, dyn, dzn, vbn);
        issue_stage(image, sid + 1, w, sxp, syp, zop, bufn);
    }
    __builtin_amdgcn_sched_barrier(0);

    // ---- phase B: LDS reads (select-free in z), interpolate, store ----
    float a0 = bufc[base00],                  a1 = bufc[base00 + 1];
    float c0 = bufc[base00 + ZWIN],           c1 = bufc[base00 + ZWIN + 1];
    float e0 = bufc[base00 + WINY * ZWIN],    e1 = bufc[base00 + WINY * ZWIN + 1];
    float g0 = bufc[base00 + (WINY + 1) * ZWIN], g1 = bufc[base00 + (WINY + 1) * ZWIN + 1];
    if (!inWin) {
        a0 = sh ? fb00.y : fb00.x;  a1 = fb00.y;
        c0 = sh ? fb01.y : fb01.x;  c1 = fb01.y;
        e0 = sh ? fb10.y : fb10.x;  e1 = fb10.y;
        g0 = sh ? fb11.y : fb11.x;  g1 = fb11.y;
    }
    float ux = 1.0f - wx, uy = 1.0f - wy, uz = 1.0f - wz;
    float res = (a0 * uz + a1 * wz) * (ux * uy)
              + (c0 * uz + c1 * wz) * (ux * wy)
              + (e0 * uz + e1 * wz) * (wx * uy)
              + (g0 * uz + g1 * wz) * (wx * wy);
    __builtin_nontemporal_store(res, out + vbc);

    // counted wait: next stage + ddf done; only our out-store may stay in flight
    asm volatile("s_waitcnt vmcnt(1)" ::: "memory");
    __builtin_amdgcn_sched_barrier(0);
    __builtin_amdgcn_s_barrier();
    __builtin_amdgcn_sched_barrier(0);
    ++sid; ++it;
}

__global__ __launch_bounds__(TPB) void warp_kernel(
    const float* __restrict__ ddf,     // [B, D, D, D, 3]
    const float* __restrict__ image,   // [B, D, D, D]
    float* __restrict__ out)           // [B, D, D, D]
{
    extern __shared__ float lds[];     // 2 * LDSPAD floats (42 KB) -> 3 WG/CU
    float* buf0 = lds;
    float* buf1 = lds + LDSPAD;

    // XCD-chunked mapping: XCD k owns a contiguous slab of blocks/tiles
    int g   = blockIdx.x;
    int gx8 = (g & 7) * (NBLK / 8) + (g >> 3);
    int sid = gx8 * CNT;

    const int tid  = threadIdx.x;
    const int w    = tid >> 6;
    const int lane = tid & 63;
    const int row  = tid / 40;              // 0..15
    const int zloc = tid - row * 40;        // 0..39 (lane z-stride 1)
    const int rx   = row >> 2, ry = row & 3;

    // hoisted per-lane stage coordinates (tile-invariant decomposition)
    int sxp[KMAX], syp[KMAX], zop[KMAX];
#pragma unroll
    for (int i = 0; i < KMAX; ++i) {
        int k = w + i * NWAVE;
        int f = k * 256 + lane * 4;
        int s = f / ZWIN;
        zop[i] = f - s * ZWIN;
        sxp[i] = s / WINY;
        syp[i] = s - sxp[i] * WINY;
    }

    float dxA, dyA, dzA, dxB, dyB, dzB;
    int vbA = 0, vbB = 0;

    // prologue: stage tile 0 + its ddf, full drain once
    issue_ddf(ddf, sid, rx, ry, zloc, dxA, dyA, dzA, vbA);
    issue_stage(image, sid, w, sxp, syp, zop, buf0);
    asm volatile("s_waitcnt vmcnt(0)" ::: "memory");
    __builtin_amdgcn_sched_barrier(0);
    __builtin_amdgcn_s_barrier();
    __builtin_amdgcn_sched_barrier(0);

    int it = 0;
    for (;;) {
        do_iter(ddf, image, out, sid, it, dxA, dyA, dzA, dxB, dyB, dzB,
                vbA, vbB, buf0, buf1, rx, ry, zloc, w, sxp, syp, zop);
        if (it >= CNT) break;
        do_iter(ddf, image, out, sid, it, dxB, dyB, dzB, dxA, dyA, dzA,
                vbB, vbA, buf1, buf0, rx, ry, zloc, w, sxp, syp, zop);
        if (it >= CNT) break;
    }
}

extern "C" void kernel_launch(void* const* d_in, const int* in_sizes, int n_in,
                              void* d_out, int out_size, void* d_ws, size_t ws_size,
                              hipStream_t stream) {
    const float* ddf   = (const float*)d_in[0];
    const float* image = (const float*)d_in[1];
    float* out = (float*)d_out;

    warp_kernel<<<NBLK, TPB, 2 * LDSPAD * sizeof(float), stream>>>(ddf, image, out);
}